// Round 5
// baseline (736.879 us; speedup 1.0000x reference)
//
#include <hip/hip_runtime.h>
#include <hip/hip_cooperative_groups.h>
#include <math.h>

namespace cg = cooperative_groups;

#define SQ2G 4.42718872424f   // sqrtf(19.6f)

#if __has_builtin(__builtin_amdgcn_sqrtf)
#define FSQRT(x) __builtin_amdgcn_sqrtf(x)
#else
#define FSQRT(x) sqrtf(x)
#endif

__device__ __forceinline__ float wave_sum(float v) {
#pragma unroll
    for (int o = 32; o > 0; o >>= 1) v += __shfl_xor(v, o);
    return v;
}

// One cooperative kernel for the whole 16-layer cascade.
// 256 blocks x 256 threads: 4 buckets/block, one wave per bucket.
// Drain = R2's proven re-ballot loop (exact spigot order: lowest-index
// candidate each round; u monotone decreasing => skipped spigots are exact 0s).
__global__ __launch_bounds__(256)
void cascade_kernel(const float* __restrict__ H0p, const float* __restrict__ Hmid,
                    const float* __restrict__ Hlast, const float* __restrict__ S0,
                    const float* __restrict__ Smid, const float* __restrict__ Slast,
                    const float* __restrict__ th0, const float* __restrict__ thmid,
                    const float* __restrict__ thlast, const float* __restrict__ precip,
                    float* __restrict__ out, float* __restrict__ PA, float* __restrict__ PB)
{
    cg::grid_group grid = cg::this_grid();
    __shared__ float acc[1024];
    const int tid  = threadIdx.x;
    const int lane = tid & 63;
    const int w    = tid >> 6;
    const int b    = blockIdx.x * 4 + w;

    const float prc = precip[0];
    const float pl  = prc * 0.0625f;            // precip / 16 (exact)
    const float pb  = pl * (1.0f / 1024.0f);    // per-bucket share (exact)

    // ---- preload mid layer 0 rows for this wave's bucket ----
    float2 sv[16]; float tv[16];
    {
        const float2* S2 = (const float2*)Smid + (size_t)b * 1024;
        const float*  th = thmid + (size_t)b * 1024;
#pragma unroll
        for (int c = 0; c < 16; ++c) { sv[c] = S2[c * 64 + lane]; tv[c] = th[c * 64 + lane]; }
    }

    // ---- layer 0: head bucket, done by block 0 / wave 0 while others park ----
    if (blockIdx.x == 0 && w == 0) {
        const float H = H0p[0];
        const float2* S2 = (const float2*)S0;
        float e0a[16], c0a[16];
#pragma unroll
        for (int c = 0; c < 16; ++c) {
            float2 s = S2[c * 64 + lane];
            float  t = th0[c * 64 + lane];
            e0a[c] = H - s.x;
            c0a[c] = t * s.y * SQ2G;
        }
        float e00 = __shfl(e0a[0], 0), c00 = __shfl(c0a[0], 0);
        float d0  = e00 + pl;
        float q0  = (d0 > 0.0f) ? c00 * FSQRT(d0) : 0.0f;
        float cum = q0;
#pragma unroll
        for (int c = 0; c < 16; ++c) {
            unsigned long long avail = (c == 0) ? ~1ull : ~0ull;
            float qm = 0.0f;
            for (;;) {
                unsigned long long cand = __ballot(e0a[c] > 0.5f * cum) & avail;
                if (!cand) break;
                int j = __builtin_ctzll(cand);
                avail = (j >= 63) ? 0ull : (~0ull << (j + 1));
                float ej = __shfl(e0a[c], j);
                float cj = __shfl(c0a[c], j);
                float q  = cj * FSQRT(fmaf(-0.5f, cum, ej));   // d > 0 by ballot
                cum += q;
                if (lane == j) qm = q;
                if (!avail) break;
            }
            int i = c * 64 + lane;
            PA[i] = (i == 0) ? q0 : qm;
        }
        if (lane == 0) out[0] = (H - cum) + pl;   // H0_new
    }
    grid.sync();

    float* cur = PA;
    float* nxt = PB;
    int npart  = 1;

    for (int l = 0; l < 14; ++l) {
        // (1) inflow-partial gather loads FIRST (oldest in vmem queue)
        float part = 0.0f;
        for (int k = lane; k < npart; k += 64) part += cur[k * 1024 + b];

        // (2) prefetch next layer's S/theta rows (in flight across the drain)
        float2 svn[16]; float tvn[16];
        if (l < 13) {
            const float2* S2 = (const float2*)Smid + ((size_t)(l + 1) * 1024 + b) * 1024;
            const float*  th = thmid + ((size_t)(l + 1) * 1024 + b) * 1024;
#pragma unroll
            for (int c = 0; c < 16; ++c) { svn[c] = S2[c * 64 + lane]; tvn[c] = th[c * 64 + lane]; }
        }

        const float H = Hmid[l * 1024 + b];
        float e[16], cc[16];
#pragma unroll
        for (int c = 0; c < 16; ++c) { e[c] = H - sv[c].x; cc[c] = tv[c] * sv[c].y * SQ2G; }

        const float inflow = pb + wave_sum(part);

#pragma unroll
        for (int r = 0; r < 4; ++r) acc[r * 256 + tid] = 0.0f;
        __syncthreads();

        // spigot 0 sees H + inflow; carry drops inflow immediately
        float e0 = __shfl(e[0], 0), c0 = __shfl(cc[0], 0);
        float d0 = e0 + inflow;
        float q0 = (d0 > 0.0f) ? c0 * FSQRT(d0) : 0.0f;
        float cum = q0;
        if (lane == 0 && q0 != 0.0f) atomicAdd(&acc[0], q0);

#pragma unroll
        for (int c = 0; c < 16; ++c) {
            unsigned long long avail = (c == 0) ? ~1ull : ~0ull;
            float qm = 0.0f;
            for (;;) {
                unsigned long long cand = __ballot(e[c] > 0.5f * cum) & avail;
                if (!cand) break;
                int j = __builtin_ctzll(cand);
                avail = (j >= 63) ? 0ull : (~0ull << (j + 1));
                float ej = __shfl(e[c], j);
                float cj = __shfl(cc[c], j);
                float q  = cj * FSQRT(fmaf(-0.5f, cum, ej));
                cum += q;
                if (lane == j) qm = q;
                if (!avail) break;
            }
            if (qm != 0.0f) atomicAdd(&acc[c * 64 + lane], qm);
        }
        if (lane == 0) out[1 + l * 1024 + b] = (H - cum) + inflow;   // H_mid_new[l][b]

        __syncthreads();
#pragma unroll
        for (int r = 0; r < 4; ++r)
            nxt[(size_t)blockIdx.x * 1024 + r * 256 + tid] = acc[r * 256 + tid];

        grid.sync();

        float* t = cur; cur = nxt; nxt = t;
        npart = 256;
#pragma unroll
        for (int c = 0; c < 16; ++c) { sv[c] = svn[c]; tv[c] = tvn[c]; }
    }

    // ---- last layer: 1 spigot per bucket, wave-per-bucket gather ----
    {
        float part = 0.0f;
#pragma unroll
        for (int k = 0; k < 4; ++k) part += cur[(k * 64 + lane) * 1024 + b];
        float inflow = pb + wave_sum(part);
        if (lane == 0) {
            float H  = Hlast[b];
            float2 s = ((const float2*)Slast)[b];
            float d  = (H + inflow) - s.x;
            float q  = (d > 0.0f) ? thlast[b] * FSQRT(19.6f * d) * s.y : 0.0f;
            out[1 + 14 * 1024 + b]        = (H - q) + inflow;   // H_last_new
            out[1 + 14 * 1024 + 1024 + b] = q;                  // q_last
        }
    }
}

extern "C" void kernel_launch(void* const* d_in, const int* in_sizes, int n_in,
                              void* d_out, int out_size, void* d_ws, size_t ws_size,
                              hipStream_t stream)
{
    (void)in_sizes; (void)n_in; (void)out_size; (void)ws_size;
    const float* H0     = (const float*)d_in[0];
    const float* Hmid   = (const float*)d_in[1];
    const float* Hlast  = (const float*)d_in[2];
    const float* S0     = (const float*)d_in[3];
    const float* Smid   = (const float*)d_in[4];
    const float* Slast  = (const float*)d_in[5];
    const float* th0    = (const float*)d_in[6];
    const float* thmid  = (const float*)d_in[7];
    const float* thlast = (const float*)d_in[8];
    const float* precip = (const float*)d_in[9];
    float* out = (float*)d_out;
    float* PA  = (float*)d_ws;                 // 1024 partial slots x 256 rows (ping)
    float* PB  = PA + (size_t)256 * 1024;      // pong

    void* args[] = { (void*)&H0, (void*)&Hmid, (void*)&Hlast, (void*)&S0, (void*)&Smid,
                     (void*)&Slast, (void*)&th0, (void*)&thmid, (void*)&thlast,
                     (void*)&precip, (void*)&out, (void*)&PA, (void*)&PB };

    hipLaunchCooperativeKernel((const void*)cascade_kernel, dim3(256), dim3(256),
                               args, 0, stream);
}